// Round 1
// baseline (950.999 us; speedup 1.0000x reference)
//
#include <hip/hip_runtime.h>

// Problem constants (from reference)
#define DIMV   512
#define NEMB   4096
#define NTOK   32768                 // B*H*W = 32*32*32
#define TOTAL  (NTOK * DIMV)         // 16,777,216

// Output layout (flat f32, concatenated in return order)
#define OFF_Q    0u                  // quantize: 16,777,216
#define OFF_DIFF 16777216u           // diff: 1
#define OFF_IND  16777217u           // embed_ind: 32,768 (written as float)
#define OFF_NE   16809985u           // new_embed: 2,097,152
#define OFF_NCS  18907137u           // new_cluster_size: 4,096
#define OFF_NEA  18911233u           // new_embed_avg: 2,097,152
// total out_size = 21,008,385

// ws layout (floats): [0..4095]=onehot, [4096]=diff_acc, [4097]=n_sum
#define WS_FLOATS (NEMB + 2)

#define DECAYF 0.99f
#define OMDF   0.01f
#define EPSF   1e-5f

// ---------------------------------------------------------------------------
// new_embed_avg base: out_nea = 0.99 * embed_avg  (atomics accumulate on top)
__global__ void k_nea_init(const float* __restrict__ embed_avg,
                           float* __restrict__ out) {
    unsigned idx = blockIdx.x * 256u + threadIdx.x;   // 8192 blocks cover 2,097,152
    out[OFF_NEA + idx] = DECAYF * embed_avg[idx];
}

// ---------------------------------------------------------------------------
// Fused: quantize gather + diff partial + embed_sum scatter + onehot + ind
__global__ __launch_bounds__(256) void k_main(const float* __restrict__ inp,
                                              const int*   __restrict__ labels,
                                              const float* __restrict__ embed,
                                              float* __restrict__ out,
                                              float* __restrict__ onehot,
                                              float* __restrict__ diff_acc) {
    float* __restrict__ nea = out + OFF_NEA;
    float acc = 0.0f;
    const unsigned stride = 2048u * 256u;             // 524,288
    for (unsigned idx = blockIdx.x * 256u + threadIdx.x; idx < TOTAL; idx += stride) {
        unsigned n = idx >> 9;        // token
        unsigned d = idx & 511u;      // dim
        int lab = labels[n];
        float q = embed[(size_t)d * NEMB + (unsigned)lab];   // embed[d, lab]
        float x = inp[idx];
        out[OFF_Q + idx] = q;
        float t = q - x;
        acc += t * t;
        atomicAdd(&nea[(size_t)d * NEMB + (unsigned)lab], OMDF * x);
        if (d == 0u) {
            out[OFF_IND + n] = (float)lab;
            atomicAdd(&onehot[lab], 1.0f);
        }
    }
    // block-reduce diff partials -> single atomic per block
    __shared__ float s[256];
    s[threadIdx.x] = acc;
    __syncthreads();
    for (int o = 128; o > 0; o >>= 1) {
        if ((int)threadIdx.x < o) s[threadIdx.x] += s[threadIdx.x + o];
        __syncthreads();
    }
    if (threadIdx.x == 0) atomicAdd(diff_acc, s[0]);
}

// ---------------------------------------------------------------------------
// new_cluster_size + n = sum(ncs) + finalize diff
__global__ void k_cluster(const float* __restrict__ cluster_size,
                          const float* __restrict__ onehot,
                          const float* __restrict__ diff_acc,
                          float* __restrict__ out,
                          float* __restrict__ n_sum) {
    unsigned e = blockIdx.x * 256u + threadIdx.x;     // 16 blocks cover 4096
    float ncs = cluster_size[e] * DECAYF + OMDF * onehot[e];
    out[OFF_NCS + e] = ncs;
    __shared__ float s[256];
    s[threadIdx.x] = ncs;
    __syncthreads();
    for (int o = 128; o > 0; o >>= 1) {
        if ((int)threadIdx.x < o) s[threadIdx.x] += s[threadIdx.x + o];
        __syncthreads();
    }
    if (threadIdx.x == 0) atomicAdd(n_sum, s[0]);
    if (blockIdx.x == 0 && threadIdx.x == 0)
        out[OFF_DIFF] = diff_acc[0] * (1.0f / (float)TOTAL);
}

// ---------------------------------------------------------------------------
// new_embed = new_embed_avg / cs[e]
__global__ void k_final(const float* __restrict__ n_sum,
                        float* __restrict__ out) {
    unsigned idx = blockIdx.x * 256u + threadIdx.x;   // 8192 blocks cover 2,097,152
    unsigned e = idx & (NEMB - 1u);
    float nsum = n_sum[0];
    float ncs  = out[OFF_NCS + e];
    float cs   = (ncs + EPSF) / (nsum + (float)NEMB * EPSF) * nsum;
    out[OFF_NE + idx] = out[OFF_NEA + idx] / cs;
}

// ---------------------------------------------------------------------------
extern "C" void kernel_launch(void* const* d_in, const int* in_sizes, int n_in,
                              void* d_out, int out_size, void* d_ws, size_t ws_size,
                              hipStream_t stream) {
    const float* inp          = (const float*)d_in[0];
    const int*   labels       = (const int*)  d_in[1];
    const float* embed        = (const float*)d_in[2];
    const float* cluster_size = (const float*)d_in[3];
    const float* embed_avg    = (const float*)d_in[4];
    float* out = (float*)d_out;

    float* onehot   = (float*)d_ws;
    float* diff_acc = onehot + NEMB;
    float* n_sum    = onehot + NEMB + 1;

    // zero the small accumulator region (ws is poisoned 0xAA before each call)
    hipMemsetAsync(d_ws, 0, WS_FLOATS * sizeof(float), stream);

    k_nea_init<<<8192, 256, 0, stream>>>(embed_avg, out);
    k_main<<<2048, 256, 0, stream>>>(inp, labels, embed, out, onehot, diff_acc);
    k_cluster<<<16, 256, 0, stream>>>(cluster_size, onehot, diff_acc, out, n_sum);
    k_final<<<8192, 256, 0, stream>>>(n_sum, out);
}

// Round 2
// 215.414 us; speedup vs baseline: 4.4148x; 4.4148x over previous
//
#include <hip/hip_runtime.h>

// Problem constants
#define DIMV   512
#define NEMB   4096
#define NTOK   32768                 // B*H*W
#define TOTAL  (NTOK * DIMV)        // 16,777,216

// Output layout (flat f32, concatenated in return order)
#define OFF_Q    0u
#define OFF_DIFF 16777216u
#define OFF_IND  16777217u
#define OFF_NE   16809985u
#define OFF_NCS  18907137u
#define OFF_NEA  18911233u

// ws layout (element offsets into float/int view)
// [0 .. 2097151]           sumT   float [NEMB][DIMV]  (8 MB)
// [2097152 .. +4095]       bin_count  int
// [2101248 .. +4095]       bin_start  int
// [2105344 .. +4095]       cursor     int
// [2109440 .. +32767]      sorted_tok int
// [2142208]                diff_acc   float
// [2142209]                n_sum      float
#define WS_SUMT    0u
#define WS_BINCNT  2097152u
#define WS_BINST   2101248u
#define WS_CURSOR  2105344u
#define WS_SORTED  2109440u
#define WS_DIFF    2142208u
#define WS_NSUM    2142209u

#define DECAYF 0.99f
#define OMDF   0.01f
#define EPSF   1e-5f

// ---------------------------------------------------------------------------
// Histogram labels + write embed_ind (as float). 128 blocks x 256.
__global__ void k_hist(const int* __restrict__ labels,
                       float* __restrict__ out,
                       int* __restrict__ bin_count) {
    int n = blockIdx.x * 256 + threadIdx.x;
    int lab = labels[n];
    out[OFF_IND + n] = (float)lab;
    atomicAdd(&bin_count[lab], 1);
}

// ---------------------------------------------------------------------------
// Exclusive prefix sum over 4096 bins. 1 block x 256 (16 bins/thread).
__global__ void k_scan(const int* __restrict__ bin_count,
                       int* __restrict__ bin_start,
                       int* __restrict__ cursor) {
    __shared__ int part[256];
    int t = threadIdx.x;
    int base = t * 16;
    int local[16];
    int s = 0;
    for (int i = 0; i < 16; ++i) { local[i] = s; s += bin_count[base + i]; }
    part[t] = s;
    __syncthreads();
    for (int o = 1; o < 256; o <<= 1) {
        int v = (t >= o) ? part[t - o] : 0;
        __syncthreads();
        part[t] += v;
        __syncthreads();
    }
    int offset = (t == 0) ? 0 : part[t - 1];
    for (int i = 0; i < 16; ++i) {
        int bs = offset + local[i];
        bin_start[base + i] = bs;
        cursor[base + i]    = bs;
    }
}

// ---------------------------------------------------------------------------
// Counting-sort scatter: token indices grouped by label. 128 blocks x 256.
__global__ void k_scatter(const int* __restrict__ labels,
                          int* __restrict__ cursor,
                          int* __restrict__ sorted_tok) {
    int n = blockIdx.x * 256 + threadIdx.x;
    int lab = labels[n];
    int pos = atomicAdd(&cursor[lab], 1);
    sorted_tok[pos] = n;
}

// ---------------------------------------------------------------------------
// One block per codebook entry e: fused quantize-gather + diff + segment sum.
// Thread t owns dims d = 2t, 2t+1 (float2 lanes -> coalesced rows).
__global__ __launch_bounds__(256) void k_perlabel(
        const float* __restrict__ inp,
        const float* __restrict__ embed,
        const int*   __restrict__ sorted_tok,
        const int*   __restrict__ bin_start,
        const int*   __restrict__ bin_count,
        float* __restrict__ out,
        float* __restrict__ sumT,
        float* __restrict__ diff_acc) {
    int e = blockIdx.x;
    int t = threadIdx.x;
    int d0 = 2 * t;
    // embed column e (stride-NEMB gather; reused for all tokens in the bin)
    float q0 = embed[(size_t)d0 * NEMB + e];
    float q1 = embed[(size_t)(d0 + 1) * NEMB + e];
    int start = bin_start[e];
    int cnt   = bin_count[e];
    float s0 = 0.f, s1 = 0.f, dacc = 0.f;
    for (int i = 0; i < cnt; ++i) {
        int n = sorted_tok[start + i];                 // uniform across block
        const float2 x2 = *(const float2*)(inp + (size_t)n * DIMV + d0);
        s0 += x2.x; s1 += x2.y;
        float t0 = q0 - x2.x, t1 = q1 - x2.y;
        dacc += t0 * t0 + t1 * t1;
        *(float2*)(out + OFF_Q + (size_t)n * DIMV + d0) = make_float2(q0, q1);
    }
    *(float2*)(sumT + (size_t)e * DIMV + d0) = make_float2(s0, s1);
    __shared__ float sh[256];
    sh[t] = dacc;
    __syncthreads();
    for (int o = 128; o > 0; o >>= 1) {
        if (t < o) sh[t] += sh[t + o];
        __syncthreads();
    }
    if (t == 0) atomicAdd(diff_acc, sh[0]);
}

// ---------------------------------------------------------------------------
// new_cluster_size + n_sum + finalize diff. 16 blocks x 256.
__global__ void k_cluster(const float* __restrict__ cluster_size,
                          const int*   __restrict__ bin_count,
                          const float* __restrict__ diff_acc,
                          float* __restrict__ out,
                          float* __restrict__ n_sum) {
    unsigned e = blockIdx.x * 256u + threadIdx.x;
    float ncs = cluster_size[e] * DECAYF + OMDF * (float)bin_count[e];
    out[OFF_NCS + e] = ncs;
    __shared__ float s[256];
    s[threadIdx.x] = ncs;
    __syncthreads();
    for (int o = 128; o > 0; o >>= 1) {
        if ((int)threadIdx.x < o) s[threadIdx.x] += s[threadIdx.x + o];
        __syncthreads();
    }
    if (threadIdx.x == 0) atomicAdd(n_sum, s[0]);
    if (blockIdx.x == 0 && threadIdx.x == 0)
        out[OFF_DIFF] = diff_acc[0] * (1.0f / (float)TOTAL);
}

// ---------------------------------------------------------------------------
// Tiled transpose of sumT [e][d] -> fused EMA + normalize writes.
// Grid 2048 (128 e-tiles x 16 d-tiles), 256 threads (32x8).
__global__ __launch_bounds__(256) void k_trans_final(
        const float* __restrict__ embed_avg,
        const float* __restrict__ sumT,
        const float* __restrict__ n_sum,
        float* __restrict__ out) {
    __shared__ float tile[32][33];
    int tx = threadIdx.x & 31;
    int ty = threadIdx.x >> 5;
    int e0 = (blockIdx.x & 127) << 5;   // e tile base
    int d0 = (blockIdx.x >> 7) << 5;    // d tile base
    for (int i = 0; i < 4; ++i) {
        int er = ty + i * 8;
        tile[er][tx] = sumT[(size_t)(e0 + er) * DIMV + d0 + tx];
    }
    __syncthreads();
    float nsum = n_sum[0];
    float ncs  = out[OFF_NCS + e0 + tx];
    float cs   = (ncs + EPSF) / (nsum + (float)NEMB * EPSF) * nsum;
    float inv  = 1.0f / cs;
    for (int i = 0; i < 4; ++i) {
        int dr = d0 + ty + i * 8;
        size_t o = (size_t)dr * NEMB + e0 + tx;
        float val = DECAYF * embed_avg[o] + OMDF * tile[tx][ty + i * 8];
        out[OFF_NEA + o] = val;
        out[OFF_NE + o]  = val * inv;
    }
}

// ---------------------------------------------------------------------------
extern "C" void kernel_launch(void* const* d_in, const int* in_sizes, int n_in,
                              void* d_out, int out_size, void* d_ws, size_t ws_size,
                              hipStream_t stream) {
    const float* inp          = (const float*)d_in[0];
    const int*   labels       = (const int*)  d_in[1];
    const float* embed        = (const float*)d_in[2];
    const float* cluster_size = (const float*)d_in[3];
    const float* embed_avg    = (const float*)d_in[4];
    float* out = (float*)d_out;

    float* wsf        = (float*)d_ws;
    float* sumT       = wsf + WS_SUMT;
    int*   bin_count  = (int*)(wsf + WS_BINCNT);
    int*   bin_start  = (int*)(wsf + WS_BINST);
    int*   cursor     = (int*)(wsf + WS_CURSOR);
    int*   sorted_tok = (int*)(wsf + WS_SORTED);
    float* diff_acc   = wsf + WS_DIFF;
    float* n_sum      = wsf + WS_NSUM;

    // zero bin_count .. n_sum (covers sorted/cursor region too; cheap)
    hipMemsetAsync(wsf + WS_BINCNT, 0, (WS_NSUM - WS_BINCNT + 1) * sizeof(float), stream);

    k_hist      <<<128,  256, 0, stream>>>(labels, out, bin_count);
    k_scan      <<<1,    256, 0, stream>>>(bin_count, bin_start, cursor);
    k_scatter   <<<128,  256, 0, stream>>>(labels, cursor, sorted_tok);
    k_perlabel  <<<4096, 256, 0, stream>>>(inp, embed, sorted_tok, bin_start,
                                           bin_count, out, sumT, diff_acc);
    k_cluster   <<<16,   256, 0, stream>>>(cluster_size, bin_count, diff_acc, out, n_sum);
    k_trans_final<<<2048,256, 0, stream>>>(embed_avg, sumT, n_sum, out);
}